// Round 9
// baseline (1343.124 us; speedup 1.0000x reference)
//
#include <hip/hip_runtime.h>

#define D 128
// dst buckets: 64 nodes (shift 6); src buckets: 256 nodes (shift 8)
#define DSH 6
#define DBW 64
#define SSH 8
#define SBW 256
#define NBD_MAX 1600

typedef __attribute__((ext_vector_type(8))) short bf16x8;
typedef __attribute__((ext_vector_type(4))) float f32x4;

__device__ __forceinline__ unsigned int f2bf(float x) {
    unsigned int u = __float_as_uint(x);
    return (u + 0x7FFFu + ((u >> 16) & 1u)) >> 16;   // RNE
}

// per-bucket histograms: dst (64-node buckets) and src (256-node buckets)
__global__ __launch_bounds__(256) void k_count(
        const int* __restrict__ src, const int* __restrict__ dst,
        int* __restrict__ bcntD, int* __restrict__ bcntS,
        int nE, int NBD, int NBS) {
    __shared__ int lhD[NBD_MAX];
    __shared__ int lhS[512];
    int t = threadIdx.x;
    for (int i = t; i < NBD_MAX; i += 256) lhD[i] = 0;
    lhS[t] = 0; lhS[t + 256] = 0;
    __syncthreads();
    int base = blockIdx.x * 4096;
    #pragma unroll
    for (int i = 0; i < 16; ++i) {
        int e = base + i * 256 + t;
        if (e < nE) {
            atomicAdd(&lhD[dst[e] >> DSH], 1);
            atomicAdd(&lhS[src[e] >> SSH], 1);
        }
    }
    __syncthreads();
    for (int i = t; i < NBD; i += 256)
        if (lhD[i]) atomicAdd(&bcntD[i], lhD[i]);
    for (int i = t; i < NBS; i += 256)
        if (lhS[i]) atomicAdd(&bcntS[i], lhS[i]);
}

// one block: exclusive scan of bcntD (<=2048) and bcntS (<=1024)
__global__ __launch_bounds__(1024) void k_scan2(
        const int* __restrict__ bcntD, const int* __restrict__ bcntS,
        int* __restrict__ bbaseD, int* __restrict__ bcurD,
        int* __restrict__ bbaseS, int* __restrict__ bcurS,
        int NBD, int NBS, int nE) {
    __shared__ int sh[1024];
    int t = threadIdx.x;
    int i0 = 2 * t, i1 = 2 * t + 1;
    int a = (i0 < NBD) ? bcntD[i0] : 0;
    int bb = (i1 < NBD) ? bcntD[i1] : 0;
    sh[t] = a + bb;
    __syncthreads();
    for (int off = 1; off < 1024; off <<= 1) {
        int u = (t >= off) ? sh[t - off] : 0;
        __syncthreads();
        sh[t] += u;
        __syncthreads();
    }
    int base = (t == 0) ? 0 : sh[t - 1];
    if (i0 < NBD) { bbaseD[i0] = base; bcurD[i0] = base; }
    if (i1 < NBD) { bbaseD[i1] = base + a; bcurD[i1] = base + a; }
    if (t == 0) bbaseD[NBD] = nE;
    __syncthreads();
    int c = (t < NBS) ? bcntS[t] : 0;
    sh[t] = c;
    __syncthreads();
    for (int off = 1; off < 1024; off <<= 1) {
        int u = (t >= off) ? sh[t - off] : 0;
        __syncthreads();
        sh[t] += u;
        __syncthreads();
    }
    int excl = (t == 0) ? 0 : sh[t - 1];
    if (t < NBS) { bbaseS[t] = excl; bcurS[t] = excl; }
    if (t == 0) bbaseS[NBS] = nE;
}

// bin packed (src<<6 | dst&63) by dst bucket, and u8(src&255) by src bucket
__global__ __launch_bounds__(256) void k_pairs(
        const int* __restrict__ src, const int* __restrict__ dst,
        int* __restrict__ bcurD, int* __restrict__ bcurS,
        unsigned int* __restrict__ pairsD, unsigned char* __restrict__ srcL,
        int nE, int NBD, int NBS) {
    __shared__ int lhD[NBD_MAX], lcD[NBD_MAX];
    __shared__ int lhS[512], lcS[512];
    int t = threadIdx.x;
    for (int i = t; i < NBD_MAX; i += 256) lhD[i] = 0;
    lhS[t] = 0; lhS[t + 256] = 0;
    __syncthreads();
    int base = blockIdx.x * 4096;
    #pragma unroll
    for (int i = 0; i < 16; ++i) {
        int e = base + i * 256 + t;
        if (e < nE) {
            atomicAdd(&lhD[dst[e] >> DSH], 1);
            atomicAdd(&lhS[src[e] >> SSH], 1);
        }
    }
    __syncthreads();
    for (int i = t; i < NBD; i += 256) {
        int c = lhD[i];
        lcD[i] = c ? atomicAdd(&bcurD[i], c) : 0;
    }
    for (int i = t; i < NBS; i += 256) {
        int c = lhS[i];
        lcS[i] = c ? atomicAdd(&bcurS[i], c) : 0;
    }
    __syncthreads();
    #pragma unroll
    for (int i = 0; i < 16; ++i) {
        int e = base + i * 256 + t;
        if (e < nE) {
            int s = src[e], d = dst[e];
            int pD = atomicAdd(&lcD[d >> DSH], 1);
            pairsD[pD] = ((unsigned)s << DSH) | (unsigned)(d & (DBW - 1));
            int pS = atomicAdd(&lcS[s >> SSH], 1);
            srcL[pS] = (unsigned char)(s & (SBW - 1));
        }
    }
}

// per src-bucket: per-node counts -> degO
__global__ __launch_bounds__(256) void k_binO(
        const unsigned char* __restrict__ srcL, const int* __restrict__ bbaseS,
        int* __restrict__ degO, int nN) {
    __shared__ int c0[SBW];
    int b = blockIdx.x, t = threadIdx.x;
    int p0 = bbaseS[b], p1 = bbaseS[b + 1];
    c0[t] = 0;
    __syncthreads();
    for (int j = p0 + t; j < p1; j += 256)
        atomicAdd(&c0[srcL[j]], 1);
    __syncthreads();
    int node = (b << SSH) + t;
    if (node < nN) degO[node] = c0[t];
}

// heatS = bf16(heat * rsqrt(max(degO,1)))
__global__ __launch_bounds__(256) void k_prep2(
        const float* __restrict__ heat, const int* __restrict__ degO,
        unsigned short* __restrict__ heatS, int nN) {
    int i = blockIdx.x * 256 + threadIdx.x;
    if (i >= nN * 32) return;
    int node = i >> 5;
    int c4 = (i & 31) << 2;
    float4 v = *reinterpret_cast<const float4*>(heat + ((size_t)node << 7) + c4);
    float sc = rsqrtf((float)max(degO[node], 1));
    unsigned int b0 = f2bf(v.x * sc), b1 = f2bf(v.y * sc);
    unsigned int b2 = f2bf(v.z * sc), b3 = f2bf(v.w * sc);
    uint2 p = make_uint2(b0 | (b1 << 16), b2 | (b3 << 16));
    *reinterpret_cast<uint2*>(heatS + ((size_t)node << 7) + c4) = p;
}

// W -> bf16, transposed: WtB[c*128 + k] = bf16(W[k*128 + c])
__global__ __launch_bounds__(256) void k_prepW(
        const float* __restrict__ W, unsigned short* __restrict__ WtB) {
    int idx = blockIdx.x * 256 + threadIdx.x;
    if (idx >= D * D) return;
    int k = idx >> 7, c = idx & 127;
    WtB[c * D + k] = (unsigned short)f2bf(W[idx]);
}

// bucket gather: one block per 64-node dst bucket; LDS fp32 accumulate;
// flush applies rsqrt(degI) and writes bf16 agg.
// acc split layout: col 2l -> word l, col 2l+1 -> word l+64 (both 2-way banks = free)
__global__ __launch_bounds__(256) void k_gbucket(
        const unsigned int* __restrict__ hu, const unsigned int* __restrict__ pairsD,
        const int* __restrict__ bbaseD, unsigned int* __restrict__ aggB, int nN) {
    __shared__ float accL[DBW * 128];
    __shared__ int degL[DBW];
    __shared__ float scaleL[DBW];
    int t = threadIdx.x;
    int w = t >> 6, l = t & 63;
    int b = blockIdx.x;
    int n0 = b << DSH;
    for (int i = t; i < DBW * 128; i += 256) accL[i] = 0.f;
    if (t < DBW) degL[t] = 0;
    __syncthreads();
    int p0 = bbaseD[b], p1 = bbaseD[b + 1];
    for (int jb = p0 + (w << 6); jb < p1; jb += 256) {
        int cnt = min(64, p1 - jb);
        unsigned pr = (l < cnt) ? pairsD[jb + l] : 0u;
        if (l < cnt) atomicAdd(&degL[pr & (DBW - 1u)], 1);
        int k = 0;
        for (; k + 8 <= cnt; k += 8) {
            unsigned q0 = (unsigned)__shfl((int)pr, k + 0);
            unsigned q1 = (unsigned)__shfl((int)pr, k + 1);
            unsigned q2 = (unsigned)__shfl((int)pr, k + 2);
            unsigned q3 = (unsigned)__shfl((int)pr, k + 3);
            unsigned q4 = (unsigned)__shfl((int)pr, k + 4);
            unsigned q5 = (unsigned)__shfl((int)pr, k + 5);
            unsigned q6 = (unsigned)__shfl((int)pr, k + 6);
            unsigned q7 = (unsigned)__shfl((int)pr, k + 7);
            unsigned u0 = hu[((size_t)(q0 >> DSH) << 6) + l];
            unsigned u1 = hu[((size_t)(q1 >> DSH) << 6) + l];
            unsigned u2 = hu[((size_t)(q2 >> DSH) << 6) + l];
            unsigned u3 = hu[((size_t)(q3 >> DSH) << 6) + l];
            unsigned u4 = hu[((size_t)(q4 >> DSH) << 6) + l];
            unsigned u5 = hu[((size_t)(q5 >> DSH) << 6) + l];
            unsigned u6 = hu[((size_t)(q6 >> DSH) << 6) + l];
            unsigned u7 = hu[((size_t)(q7 >> DSH) << 6) + l];
            #define ACC1(qq, uu) { \
                int dl_ = (int)(qq & (DBW - 1u)); \
                unsafeAtomicAdd(&accL[dl_ * 128 + l], __uint_as_float(uu << 16)); \
                unsafeAtomicAdd(&accL[dl_ * 128 + 64 + l], __uint_as_float(uu & 0xFFFF0000u)); }
            ACC1(q0, u0) ACC1(q1, u1) ACC1(q2, u2) ACC1(q3, u3)
            ACC1(q4, u4) ACC1(q5, u5) ACC1(q6, u6) ACC1(q7, u7)
        }
        for (; k < cnt; ++k) {
            unsigned qq = (unsigned)__shfl((int)pr, k);
            unsigned uu = hu[((size_t)(qq >> DSH) << 6) + l];
            ACC1(qq, uu)
            #undef ACC1
        }
    }
    __syncthreads();
    if (t < DBW) scaleL[t] = rsqrtf((float)max(degL[t], 1));
    __syncthreads();
    #pragma unroll
    for (int rep = 0; rep < 16; ++rep) {
        int idx = rep * 256 + t;
        int node = idx >> 6, ju = idx & 63;
        int gn = n0 + node;
        if (gn < nN) {
            float s = scaleL[node];
            float lo = accL[node * 128 + ju] * s;
            float hi = accL[node * 128 + 64 + ju] * s;
            aggB[((size_t)gn << 6) + ju] = f2bf(lo) | (f2bf(hi) << 16);
        }
    }
}

// MFMA gemm: h(bf16) = prelu( aggB @ W + b , a1 ), stats
#define BM 64
__global__ __launch_bounds__(256) void k_gemm(
        const unsigned short* __restrict__ aggB, const unsigned short* __restrict__ WtB,
        const float* __restrict__ b, const float* __restrict__ a1,
        unsigned short* __restrict__ hB,
        float* __restrict__ sums, float* __restrict__ sumsq, int nN) {
    __shared__ unsigned short sW[128 * 136];
    __shared__ float ss1[128], ss2[128];
    int t = threadIdx.x;
    {
        const unsigned int* Wu = (const unsigned int*)WtB;
        #pragma unroll
        for (int i = 0; i < 32; ++i) {
            int idx = t + i * 256;
            int c = idx >> 6;
            int kp = idx & 63;
            *(unsigned int*)&sW[c * 136 + kp * 2] = Wu[idx];
        }
    }
    if (t < 128) { ss1[t] = 0.f; ss2[t] = 0.f; }
    __syncthreads();

    int w = t >> 6;
    int l = t & 63;
    int lr = l & 15;
    int lq = l >> 4;
    int rowbase = blockIdx.x * BM + w * 16;

    f32x4 acc[8];
    #pragma unroll
    for (int ct = 0; ct < 8; ++ct) acc[ct] = (f32x4){0.f, 0.f, 0.f, 0.f};

    int arow = rowbase + lr;
    if (arow >= nN) arow = nN - 1;
    const unsigned short* arowp = aggB + ((size_t)arow << 7);

    #pragma unroll
    for (int ks = 0; ks < 4; ++ks) {
        bf16x8 afrag = *reinterpret_cast<const bf16x8*>(arowp + ks * 32 + lq * 8);
        #pragma unroll
        for (int ct = 0; ct < 8; ++ct) {
            bf16x8 bfrag = *reinterpret_cast<const bf16x8*>(
                &sW[(ct * 16 + lr) * 136 + ks * 32 + lq * 8]);
            acc[ct] = __builtin_amdgcn_mfma_f32_16x16x32_bf16(afrag, bfrag, acc[ct], 0, 0, 0);
        }
    }

    float alpha = a1[0];
    int nv[4];
    #pragma unroll
    for (int j = 0; j < 4; ++j) nv[j] = rowbase + lq * 4 + j;
    #pragma unroll
    for (int ct = 0; ct < 8; ++ct) {
        int f = ct * 16 + lr;
        float bias = b[f];
        float p1 = 0.f, p2 = 0.f;
        #pragma unroll
        for (int j = 0; j < 4; ++j) {
            if (nv[j] < nN) {
                float v = acc[ct][j] + bias;
                v = v > 0.f ? v : alpha * v;
                hB[((size_t)nv[j] << 7) + f] = (unsigned short)f2bf(v);
                p1 += v; p2 += v * v;
            }
        }
        atomicAdd(&ss1[f], p1);
        atomicAdd(&ss2[f], p2);
    }
    __syncthreads();
    if (t < 128) {
        int slot = blockIdx.x & 15;
        atomicAdd(&sums[slot * D + t], ss1[t]);
        atomicAdd(&sumsq[slot * D + t], ss2[t]);
    }
}

__global__ void k_finalize(
        const float* __restrict__ sums, const float* __restrict__ sumsq,
        const float* __restrict__ gamma, const float* __restrict__ beta,
        float* __restrict__ stats, int nN) {
    int f = threadIdx.x;
    float s1 = 0.f, s2 = 0.f;
    #pragma unroll
    for (int i = 0; i < 16; ++i) { s1 += sums[i * D + f]; s2 += sumsq[i * D + f]; }
    float inv_n = 1.0f / (float)nN;
    float mean = s1 * inv_n;
    float var = s2 * inv_n - mean * mean;
    float inv = rsqrtf(var + 1e-5f);
    float sc = gamma[f] * inv;
    stats[f] = sc;
    stats[D + f] = beta[f] - mean * sc;
}

// BN + PReLU: read bf16 h, write fp32 out
__global__ __launch_bounds__(256) void k_apply(
        const unsigned int* __restrict__ hB, const float* __restrict__ stats,
        const float* __restrict__ a2, float* __restrict__ out, int total2) {
    int idx = blockIdx.x * 256 + threadIdx.x;
    if (idx >= total2) return;
    float alpha = a2[0];
    int j = idx & 31;                   // uint2 within row -> cols 4j..4j+3
    uint2 p = reinterpret_cast<const uint2*>(hB)[idx];
    float4 sc = *reinterpret_cast<const float4*>(stats + (j << 2));
    float4 sh = *reinterpret_cast<const float4*>(stats + D + (j << 2));
    float4 r;
    float v0 = __uint_as_float(p.x << 16);
    float v1 = __uint_as_float(p.x & 0xFFFF0000u);
    float v2 = __uint_as_float(p.y << 16);
    float v3 = __uint_as_float(p.y & 0xFFFF0000u);
    r.x = v0 * sc.x + sh.x; r.x = r.x > 0.f ? r.x : alpha * r.x;
    r.y = v1 * sc.y + sh.y; r.y = r.y > 0.f ? r.y : alpha * r.y;
    r.z = v2 * sc.z + sh.z; r.z = r.z > 0.f ? r.z : alpha * r.z;
    r.w = v3 * sc.w + sh.w; r.w = r.w > 0.f ? r.w : alpha * r.w;
    reinterpret_cast<float4*>(out)[idx] = r;
}

extern "C" void kernel_launch(void* const* d_in, const int* in_sizes, int n_in,
                              void* d_out, int out_size, void* d_ws, size_t ws_size,
                              hipStream_t stream) {
    const float* heat  = (const float*)d_in[0];
    const float* W     = (const float*)d_in[1];
    const float* b     = (const float*)d_in[2];
    const float* a1    = (const float*)d_in[3];
    const float* gamma = (const float*)d_in[4];
    const float* beta  = (const float*)d_in[5];
    const float* a2    = (const float*)d_in[6];
    const int*   src   = (const int*)d_in[7];
    const int*   dst   = (const int*)d_in[8];

    const int nN = in_sizes[0] / D;
    const int nE = in_sizes[7];
    const int NBD = (nN + DBW - 1) >> DSH;     // 64-node dst buckets (1563)
    const int NBS = (nN + SBW - 1) >> SSH;     // 256-node src buckets (391)
    const int nEB = (nE + 4095) / 4096;

    char* ws = (char*)d_ws;
    size_t o = 0;
    auto alloc = [&](size_t bytes) { size_t r = o; o = (o + bytes + 255) & ~(size_t)255; return r; };
    int*   bcntD = (int*)(ws + alloc(NBD_MAX * 4));
    int*   bcntS = (int*)(ws + alloc(512 * 4));
    float* sums  = (float*)(ws + alloc(16 * D * 4));
    float* sumsq = (float*)(ws + alloc(16 * D * 4));
    size_t zero_end = o;
    int*   bbaseD = (int*)(ws + alloc((NBD_MAX + 1) * 4));
    int*   bcurD  = (int*)(ws + alloc(NBD_MAX * 4));
    int*   bbaseS = (int*)(ws + alloc(512 * 4));
    int*   bcurS  = (int*)(ws + alloc(512 * 4));
    float* stats  = (float*)(ws + alloc(2 * D * 4));
    unsigned short* WtB = (unsigned short*)(ws + alloc((size_t)D * D * 2));
    int*   degO   = (int*)(ws + alloc((size_t)nN * 4));
    size_t alias0 = o;                          // hB aliases pairsD+srcL+heatS (dead after k_gbucket)
    unsigned int*  pairsD = (unsigned int*)(ws + alloc((size_t)nE * 4));
    unsigned char* srcL   = (unsigned char*)(ws + alloc((size_t)nE));
    unsigned short* heatS = (unsigned short*)(ws + alloc((size_t)nN * D * 2));
    unsigned int*  aggB   = (unsigned int*)(ws + alloc((size_t)nN * D * 2));
    unsigned short* hB    = (unsigned short*)(ws + alias0);
    float* outp = (float*)d_out;

    hipMemsetAsync(ws, 0, zero_end, stream);

    k_count<<<nEB, 256, 0, stream>>>(src, dst, bcntD, bcntS, nE, NBD, NBS);
    k_scan2<<<1, 1024, 0, stream>>>(bcntD, bcntS, bbaseD, bcurD, bbaseS, bcurS, NBD, NBS, nE);
    k_pairs<<<nEB, 256, 0, stream>>>(src, dst, bcurD, bcurS, pairsD, srcL, nE, NBD, NBS);
    k_binO<<<NBS, 256, 0, stream>>>(srcL, bbaseS, degO, nN);
    k_prepW<<<(D * D + 255) / 256, 256, 0, stream>>>(W, WtB);
    k_prep2<<<(nN * 32 + 255) / 256, 256, 0, stream>>>(heat, degO, heatS, nN);
    k_gbucket<<<NBD, 256, 0, stream>>>(
        (const unsigned int*)heatS, pairsD, bbaseD, aggB, nN);
    k_gemm<<<(nN + BM - 1) / BM, 256, 0, stream>>>(
        (const unsigned short*)aggB, WtB, b, a1, hB, sums, sumsq, nN);
    k_finalize<<<1, 128, 0, stream>>>(sums, sumsq, gamma, beta, stats, nN);
    k_apply<<<(nN * 32 + 255) / 256, 256, 0, stream>>>(
        (const unsigned int*)hB, stats, a2, outp, nN * 32);
}

// Round 10
// 217.619 us; speedup vs baseline: 6.1719x; 6.1719x over previous
//
#include <hip/hip_runtime.h>

#define D 128
#define BSH 9
#define BW 512

typedef __attribute__((ext_vector_type(8))) short bf16x8;
typedef __attribute__((ext_vector_type(4))) float f32x4;

__device__ __forceinline__ unsigned int f2bf(float x) {
    unsigned int u = __float_as_uint(x);
    return (u + 0x7FFFu + ((u >> 16) & 1u)) >> 16;   // RNE
}

// per-bucket histograms of dst AND src (bucket = id>>9)
__global__ __launch_bounds__(256) void k_count(
        const int* __restrict__ src, const int* __restrict__ dst,
        int* __restrict__ bcntD, int* __restrict__ bcntS, int nE, int NBK) {
    __shared__ int lhD[256], lhS[256];
    int t = threadIdx.x;
    lhD[t] = 0; lhS[t] = 0;
    __syncthreads();
    int base = blockIdx.x * 4096;
    #pragma unroll
    for (int i = 0; i < 16; ++i) {
        int e = base + i * 256 + t;
        if (e < nE) {
            atomicAdd(&lhD[dst[e] >> BSH], 1);
            atomicAdd(&lhS[src[e] >> BSH], 1);
        }
    }
    __syncthreads();
    if (t < NBK) {
        if (lhD[t]) atomicAdd(&bcntD[t], lhD[t]);
        if (lhS[t]) atomicAdd(&bcntS[t], lhS[t]);
    }
}

__global__ __launch_bounds__(256) void k_bscan2(
        const int* __restrict__ bcntD, const int* __restrict__ bcntS,
        int* __restrict__ bbaseD, int* __restrict__ bcurD,
        int* __restrict__ bbaseS, int* __restrict__ bcurS, int NBK, int nE) {
    __shared__ int sh[256];
    int t = threadIdx.x;
    sh[t] = (t < NBK) ? bcntD[t] : 0;
    __syncthreads();
    for (int off = 1; off < 256; off <<= 1) {
        int u = (t >= off) ? sh[t - off] : 0;
        __syncthreads();
        sh[t] += u;
        __syncthreads();
    }
    if (t < NBK) {
        int excl = (t == 0) ? 0 : sh[t - 1];
        bbaseD[t] = excl; bcurD[t] = excl;
    }
    if (t == 0) bbaseD[NBK] = nE;
    __syncthreads();
    sh[t] = (t < NBK) ? bcntS[t] : 0;
    __syncthreads();
    for (int off = 1; off < 256; off <<= 1) {
        int u = (t >= off) ? sh[t - off] : 0;
        __syncthreads();
        sh[t] += u;
        __syncthreads();
    }
    if (t < NBK) {
        int excl = (t == 0) ? 0 : sh[t - 1];
        bbaseS[t] = excl; bcurS[t] = excl;
    }
    if (t == 0) bbaseS[NBK] = nE;
}

__global__ __launch_bounds__(256) void k_pairs(
        const int* __restrict__ src, const int* __restrict__ dst,
        int* __restrict__ bcurD, int* __restrict__ bcurS,
        unsigned int* __restrict__ pairsD, unsigned short* __restrict__ srcL,
        int nE) {
    __shared__ int lhD[256], lcD[256], lhS[256], lcS[256];
    int t = threadIdx.x;
    lhD[t] = 0; lhS[t] = 0;
    __syncthreads();
    int base = blockIdx.x * 4096;
    #pragma unroll
    for (int i = 0; i < 16; ++i) {
        int e = base + i * 256 + t;
        if (e < nE) {
            atomicAdd(&lhD[dst[e] >> BSH], 1);
            atomicAdd(&lhS[src[e] >> BSH], 1);
        }
    }
    __syncthreads();
    int cD = lhD[t];
    lcD[t] = cD ? atomicAdd(&bcurD[t], cD) : 0;
    int cS = lhS[t];
    lcS[t] = cS ? atomicAdd(&bcurS[t], cS) : 0;
    __syncthreads();
    #pragma unroll
    for (int i = 0; i < 16; ++i) {
        int e = base + i * 256 + t;
        if (e < nE) {
            int s = src[e], d = dst[e];
            int pD = atomicAdd(&lcD[d >> BSH], 1);
            pairsD[pD] = ((unsigned)s << BSH) | (unsigned)(d & (BW - 1));
            int pS = atomicAdd(&lcS[s >> BSH], 1);
            srcL[pS] = (unsigned short)(s & (BW - 1));
        }
    }
}

__global__ __launch_bounds__(512) void k_binD(
        const unsigned int* __restrict__ pairsD, const int* __restrict__ bbaseD,
        int* __restrict__ degI, int* __restrict__ offs,
        int* __restrict__ elist, int nN) {
    __shared__ int c0[BW], sh[BW], lcur[BW];
    int b = blockIdx.x, t = threadIdx.x;
    int p0 = bbaseD[b], p1 = bbaseD[b + 1];
    int n0 = b << BSH;
    c0[t] = 0;
    __syncthreads();
    for (int j = p0 + t; j < p1; j += 512)
        atomicAdd(&c0[pairsD[j] & (BW - 1u)], 1);
    __syncthreads();
    sh[t] = c0[t];
    __syncthreads();
    for (int off = 1; off < BW; off <<= 1) {
        int u = (t >= off) ? sh[t - off] : 0;
        __syncthreads();
        sh[t] += u;
        __syncthreads();
    }
    int excl = (t == 0) ? 0 : sh[t - 1];
    int node = n0 + t;
    if (node < nN) { degI[node] = c0[t]; offs[node] = p0 + excl; }
    lcur[t] = p0 + excl;
    __syncthreads();
    for (int j = p0 + t; j < p1; j += 512) {
        unsigned int pr = pairsD[j];
        int pos = atomicAdd(&lcur[pr & (BW - 1u)], 1);
        elist[pos] = (int)(pr >> BSH);
    }
}

__global__ __launch_bounds__(512) void k_binO(
        const unsigned short* __restrict__ srcL, const int* __restrict__ bbaseS,
        int* __restrict__ degO, int nN) {
    __shared__ int c0[BW];
    int b = blockIdx.x, t = threadIdx.x;
    int p0 = bbaseS[b], p1 = bbaseS[b + 1];
    c0[t] = 0;
    __syncthreads();
    for (int j = p0 + t; j < p1; j += 512)
        atomicAdd(&c0[srcL[j]], 1);
    __syncthreads();
    int node = (b << BSH) + t;
    if (node < nN) degO[node] = c0[t];
}

__global__ __launch_bounds__(256) void k_prep2(
        const float* __restrict__ heat, const int* __restrict__ degO,
        unsigned short* __restrict__ heatS, int nN) {
    int i = blockIdx.x * 256 + threadIdx.x;
    if (i >= nN * 32) return;
    int node = i >> 5;
    int c4 = (i & 31) << 2;
    float4 v = *reinterpret_cast<const float4*>(heat + ((size_t)node << 7) + c4);
    float sc = rsqrtf((float)max(degO[node], 1));
    unsigned int b0 = f2bf(v.x * sc), b1 = f2bf(v.y * sc);
    unsigned int b2 = f2bf(v.z * sc), b3 = f2bf(v.w * sc);
    uint2 p = make_uint2(b0 | (b1 << 16), b2 | (b3 << 16));
    *reinterpret_cast<uint2*>(heatS + ((size_t)node << 7) + c4) = p;
}

// W -> bf16, transposed: WtB[c*128 + k] = bf16(W[k*128 + c])
__global__ __launch_bounds__(256) void k_prepW(
        const float* __restrict__ W, unsigned short* __restrict__ WtB) {
    int idx = blockIdx.x * 256 + threadIdx.x;
    if (idx >= D * D) return;
    int k = idx >> 7, c = idx & 127;
    WtB[c * D + k] = (unsigned short)f2bf(W[idx]);
}

// one wave per node, 8-deep MLP; output bf16 raw sums
__global__ __launch_bounds__(256) void k_gather(
        const unsigned short* __restrict__ heatS, const int* __restrict__ elist,
        const int* __restrict__ offs, const int* __restrict__ degI,
        unsigned int* __restrict__ aggB, int nN) {
    int node = blockIdx.x * 4 + (threadIdx.x >> 6);
    if (node >= nN) return;
    int l = threadIdx.x & 63;
    size_t col = (size_t)(l << 1);
    int start = offs[node];
    int end = start + degI[node];
    float ax = 0.f, ay = 0.f;
    for (int jb = start; jb < end; jb += 64) {
        int cnt = min(64, end - jb);
        int sl = (l < cnt) ? elist[jb + l] : 0;
        int k = 0;
        for (; k + 8 <= cnt; k += 8) {
            unsigned int p0, p1, p2, p3, p4, p5, p6, p7;
            {
                int s0 = __shfl(sl, k + 0), s1 = __shfl(sl, k + 1);
                int s2 = __shfl(sl, k + 2), s3 = __shfl(sl, k + 3);
                int s4 = __shfl(sl, k + 4), s5 = __shfl(sl, k + 5);
                int s6 = __shfl(sl, k + 6), s7 = __shfl(sl, k + 7);
                p0 = *reinterpret_cast<const unsigned int*>(heatS + ((size_t)s0 << 7) + col);
                p1 = *reinterpret_cast<const unsigned int*>(heatS + ((size_t)s1 << 7) + col);
                p2 = *reinterpret_cast<const unsigned int*>(heatS + ((size_t)s2 << 7) + col);
                p3 = *reinterpret_cast<const unsigned int*>(heatS + ((size_t)s3 << 7) + col);
                p4 = *reinterpret_cast<const unsigned int*>(heatS + ((size_t)s4 << 7) + col);
                p5 = *reinterpret_cast<const unsigned int*>(heatS + ((size_t)s5 << 7) + col);
                p6 = *reinterpret_cast<const unsigned int*>(heatS + ((size_t)s6 << 7) + col);
                p7 = *reinterpret_cast<const unsigned int*>(heatS + ((size_t)s7 << 7) + col);
            }
            ax += __uint_as_float(p0 << 16) + __uint_as_float(p1 << 16)
                + __uint_as_float(p2 << 16) + __uint_as_float(p3 << 16)
                + __uint_as_float(p4 << 16) + __uint_as_float(p5 << 16)
                + __uint_as_float(p6 << 16) + __uint_as_float(p7 << 16);
            ay += __uint_as_float(p0 & 0xFFFF0000u) + __uint_as_float(p1 & 0xFFFF0000u)
                + __uint_as_float(p2 & 0xFFFF0000u) + __uint_as_float(p3 & 0xFFFF0000u)
                + __uint_as_float(p4 & 0xFFFF0000u) + __uint_as_float(p5 & 0xFFFF0000u)
                + __uint_as_float(p6 & 0xFFFF0000u) + __uint_as_float(p7 & 0xFFFF0000u);
        }
        for (; k < cnt; ++k) {
            int s = __shfl(sl, k);
            unsigned int p = *reinterpret_cast<const unsigned int*>(heatS + ((size_t)s << 7) + col);
            ax += __uint_as_float(p << 16);
            ay += __uint_as_float(p & 0xFFFF0000u);
        }
    }
    aggB[((size_t)node << 6) + l] = f2bf(ax) | (f2bf(ay) << 16);
}

// MFMA gemm: hB(bf16) = prelu( rsqrt(degI) * (aggB @ W) + b , a1 ), stats
#define BM 64
__global__ __launch_bounds__(256) void k_gemm(
        const unsigned short* __restrict__ aggB, const unsigned short* __restrict__ WtB,
        const float* __restrict__ b, const int* __restrict__ degI,
        const float* __restrict__ a1, unsigned short* __restrict__ hB,
        float* __restrict__ sums, float* __restrict__ sumsq, int nN) {
    __shared__ unsigned short sW[128 * 136];    // Wt padded: row c at c*136, 16B-aligned frags
    __shared__ float ss1[128], ss2[128];
    int t = threadIdx.x;
    {
        const unsigned int* Wu = (const unsigned int*)WtB;
        #pragma unroll
        for (int i = 0; i < 32; ++i) {
            int idx = t + i * 256;              // 8192 uints
            int c = idx >> 6;
            int kp = idx & 63;
            *(unsigned int*)&sW[c * 136 + kp * 2] = Wu[idx];
        }
    }
    if (t < 128) { ss1[t] = 0.f; ss2[t] = 0.f; }
    __syncthreads();

    int w = t >> 6;
    int l = t & 63;
    int lr = l & 15;        // A row-in-tile / B col-in-tile / C col
    int lq = l >> 4;        // k-group / C row-group
    int rowbase = blockIdx.x * BM + w * 16;

    f32x4 acc[8];
    #pragma unroll
    for (int ct = 0; ct < 8; ++ct) acc[ct] = (f32x4){0.f, 0.f, 0.f, 0.f};

    int arow = rowbase + lr;
    if (arow >= nN) arow = nN - 1;
    const unsigned short* arowp = aggB + ((size_t)arow << 7);

    #pragma unroll
    for (int ks = 0; ks < 4; ++ks) {
        bf16x8 afrag = *reinterpret_cast<const bf16x8*>(arowp + ks * 32 + lq * 8);
        #pragma unroll
        for (int ct = 0; ct < 8; ++ct) {
            bf16x8 bfrag = *reinterpret_cast<const bf16x8*>(
                &sW[(ct * 16 + lr) * 136 + ks * 32 + lq * 8]);
            acc[ct] = __builtin_amdgcn_mfma_f32_16x16x32_bf16(afrag, bfrag, acc[ct], 0, 0, 0);
        }
    }

    float alpha = a1[0];
    float s4v[4];
    int nv[4];
    #pragma unroll
    for (int j = 0; j < 4; ++j) {
        int n = rowbase + lq * 4 + j;
        nv[j] = n;
        s4v[j] = (n < nN) ? rsqrtf((float)max(degI[n], 1)) : 0.f;
    }
    #pragma unroll
    for (int ct = 0; ct < 8; ++ct) {
        int f = ct * 16 + lr;
        float bias = b[f];
        float p1 = 0.f, p2 = 0.f;
        #pragma unroll
        for (int j = 0; j < 4; ++j) {
            if (nv[j] < nN) {
                float v = acc[ct][j] * s4v[j] + bias;
                v = v > 0.f ? v : alpha * v;
                hB[((size_t)nv[j] << 7) + f] = (unsigned short)f2bf(v);
                p1 += v; p2 += v * v;
            }
        }
        atomicAdd(&ss1[f], p1);
        atomicAdd(&ss2[f], p2);
    }
    __syncthreads();
    if (t < 128) {
        int slot = blockIdx.x & 15;
        atomicAdd(&sums[slot * D + t], ss1[t]);
        atomicAdd(&sumsq[slot * D + t], ss2[t]);
    }
}

__global__ void k_finalize(
        const float* __restrict__ sums, const float* __restrict__ sumsq,
        const float* __restrict__ gamma, const float* __restrict__ beta,
        float* __restrict__ stats, int nN) {
    int f = threadIdx.x;
    float s1 = 0.f, s2 = 0.f;
    #pragma unroll
    for (int i = 0; i < 16; ++i) { s1 += sums[i * D + f]; s2 += sumsq[i * D + f]; }
    float inv_n = 1.0f / (float)nN;
    float mean = s1 * inv_n;
    float var = s2 * inv_n - mean * mean;
    float inv = rsqrtf(var + 1e-5f);
    float sc = gamma[f] * inv;
    stats[f] = sc;
    stats[D + f] = beta[f] - mean * sc;
}

// BN + PReLU: read bf16 h, write fp32 out
__global__ __launch_bounds__(256) void k_apply(
        const unsigned int* __restrict__ hB2, const float* __restrict__ stats,
        const float* __restrict__ a2, float* __restrict__ out, int total2) {
    int idx = blockIdx.x * 256 + threadIdx.x;
    if (idx >= total2) return;
    float alpha = a2[0];
    int j = idx & 31;                   // uint2 within row -> cols 4j..4j+3
    uint2 p = reinterpret_cast<const uint2*>(hB2)[idx];
    float4 sc = *reinterpret_cast<const float4*>(stats + (j << 2));
    float4 sh = *reinterpret_cast<const float4*>(stats + D + (j << 2));
    float4 r;
    float v0 = __uint_as_float(p.x << 16);
    float v1 = __uint_as_float(p.x & 0xFFFF0000u);
    float v2 = __uint_as_float(p.y << 16);
    float v3 = __uint_as_float(p.y & 0xFFFF0000u);
    r.x = v0 * sc.x + sh.x; r.x = r.x > 0.f ? r.x : alpha * r.x;
    r.y = v1 * sc.y + sh.y; r.y = r.y > 0.f ? r.y : alpha * r.y;
    r.z = v2 * sc.z + sh.z; r.z = r.z > 0.f ? r.z : alpha * r.z;
    r.w = v3 * sc.w + sh.w; r.w = r.w > 0.f ? r.w : alpha * r.w;
    reinterpret_cast<float4*>(out)[idx] = r;
}

extern "C" void kernel_launch(void* const* d_in, const int* in_sizes, int n_in,
                              void* d_out, int out_size, void* d_ws, size_t ws_size,
                              hipStream_t stream) {
    const float* heat  = (const float*)d_in[0];
    const float* W     = (const float*)d_in[1];
    const float* b     = (const float*)d_in[2];
    const float* a1    = (const float*)d_in[3];
    const float* gamma = (const float*)d_in[4];
    const float* beta  = (const float*)d_in[5];
    const float* a2    = (const float*)d_in[6];
    const int*   src   = (const int*)d_in[7];
    const int*   dst   = (const int*)d_in[8];

    const int nN = in_sizes[0] / D;
    const int nE = in_sizes[7];
    const int NBK = (nN + BW - 1) >> BSH;
    const int nEB = (nE + 4095) / 4096;

    char* ws = (char*)d_ws;
    size_t o = 0;
    auto alloc = [&](size_t bytes) { size_t r = o; o = (o + bytes + 255) & ~(size_t)255; return r; };
    int*   bcntD = (int*)(ws + alloc(256 * 4));
    int*   bcntS = (int*)(ws + alloc(256 * 4));
    float* sums  = (float*)(ws + alloc(16 * D * 4));
    float* sumsq = (float*)(ws + alloc(16 * D * 4));
    size_t zero_end = o;
    int*   bbaseD = (int*)(ws + alloc(257 * 4));
    int*   bcurD  = (int*)(ws + alloc(256 * 4));
    int*   bbaseS = (int*)(ws + alloc(257 * 4));
    int*   bcurS  = (int*)(ws + alloc(256 * 4));
    float* stats  = (float*)(ws + alloc(2 * D * 4));
    unsigned short* WtB = (unsigned short*)(ws + alloc((size_t)D * D * 2));
    int*   degO   = (int*)(ws + alloc((size_t)nN * 4));
    int*   degI   = (int*)(ws + alloc((size_t)nN * 4));
    int*   offs   = (int*)(ws + alloc((size_t)nN * 4));
    int*   elist  = (int*)(ws + alloc(((size_t)nE + 64) * 4));  // +pad for overread
    // aliased region: pairsD+srcL+heatS are all dead before k_gemm writes hB
    size_t alias0 = o;
    unsigned int*   pairsD = (unsigned int*)(ws + alloc((size_t)nE * 4));
    unsigned short* srcL   = (unsigned short*)(ws + alloc((size_t)nE * 2));
    unsigned short* heatS  = (unsigned short*)(ws + alloc((size_t)nN * D * 2));
    unsigned int*   aggB   = (unsigned int*)(ws + alloc((size_t)nN * D * 2));
    unsigned short* hB     = (unsigned short*)(ws + alias0);    // 25.6 MB ⊂ 35.2 MB region
    float* outp = (float*)d_out;

    hipMemsetAsync(ws, 0, zero_end, stream);

    k_count<<<nEB, 256, 0, stream>>>(src, dst, bcntD, bcntS, nE, NBK);
    k_bscan2<<<1, 256, 0, stream>>>(bcntD, bcntS, bbaseD, bcurD, bbaseS, bcurS, NBK, nE);
    k_pairs<<<nEB, 256, 0, stream>>>(src, dst, bcurD, bcurS, pairsD, srcL, nE);
    k_binD<<<NBK, 512, 0, stream>>>(pairsD, bbaseD, degI, offs, elist, nN);
    k_binO<<<NBK, 512, 0, stream>>>(srcL, bbaseS, degO, nN);
    k_prepW<<<(D * D + 255) / 256, 256, 0, stream>>>(W, WtB);
    k_prep2<<<(nN * 32 + 255) / 256, 256, 0, stream>>>(heat, degO, heatS, nN);
    k_gather<<<(nN + 3) / 4, 256, 0, stream>>>(heatS, elist, offs, degI, aggB, nN);
    k_gemm<<<(nN + BM - 1) / BM, 256, 0, stream>>>(
        (const unsigned short*)aggB, WtB, b, degI, a1, hB, sums, sumsq, nN);
    k_finalize<<<1, 128, 0, stream>>>(sums, sumsq, gamma, beta, stats, nN);
    k_apply<<<(nN * 32 + 255) / 256, 256, 0, stream>>>(
        (const unsigned int*)hB, stats, a2, outp, nN * 32);
}

// Round 11
// 207.838 us; speedup vs baseline: 6.4624x; 1.0471x over previous
//
#include <hip/hip_runtime.h>

#define D 128
#define BSH 9
#define BW 512

typedef __attribute__((ext_vector_type(8))) short bf16x8;
typedef __attribute__((ext_vector_type(4))) float f32x4;

__device__ __forceinline__ unsigned int f2bf(float x) {
    unsigned int u = __float_as_uint(x);
    return (u + 0x7FFFu + ((u >> 16) & 1u)) >> 16;   // RNE
}

// phase 1: per-block LDS hist of dst/src buckets -> cnt matrices [bucket][block]
__global__ __launch_bounds__(256) void k_hist(
        const int* __restrict__ src, const int* __restrict__ dst,
        unsigned int* __restrict__ cntD, unsigned int* __restrict__ cntS,
        int nE, int NBK, int nEB) {
    __shared__ int lhD[256], lhS[256];
    int t = threadIdx.x, b = blockIdx.x;
    lhD[t] = 0; lhS[t] = 0;
    __syncthreads();
    int base = b * 4096;
    #pragma unroll
    for (int i = 0; i < 16; ++i) {
        int e = base + i * 256 + t;
        if (e < nE) {
            atomicAdd(&lhD[dst[e] >> BSH], 1);
            atomicAdd(&lhS[src[e] >> BSH], 1);
        }
    }
    __syncthreads();
    for (int c = t; c < NBK; c += 256) {
        cntD[c * nEB + b] = (unsigned)lhD[c];
        cntS[c * nEB + b] = (unsigned)lhS[c];
    }
}

// phase 2: per-bucket exclusive scan across blocks (in-place), emit column sums
// requires nEB <= 512
__global__ __launch_bounds__(512) void k_colscan(
        unsigned int* __restrict__ cntD, unsigned int* __restrict__ cntS,
        unsigned int* __restrict__ colsumD, unsigned int* __restrict__ colsumS,
        int NBK, int nEB) {
    __shared__ unsigned int sh[512];
    int t = threadIdx.x;
    int c = blockIdx.x;
    unsigned int* cnt;
    unsigned int* cs;
    if (c < NBK) { cnt = cntD; cs = colsumD; }
    else { cnt = cntS; cs = colsumS; c -= NBK; }
    unsigned v = (t < nEB) ? cnt[c * nEB + t] : 0u;
    sh[t] = v;
    __syncthreads();
    for (int off = 1; off < 512; off <<= 1) {
        unsigned u = (t >= off) ? sh[t - off] : 0u;
        __syncthreads();
        sh[t] += u;
        __syncthreads();
    }
    if (t < nEB) cnt[c * nEB + t] = sh[t] - v;      // exclusive prefix in-place
    if (t == 511) cs[c] = sh[511];
}

// phase 3: scan bucket sums -> global bucket bases
__global__ __launch_bounds__(256) void k_bscan3(
        const unsigned int* __restrict__ colsumD, const unsigned int* __restrict__ colsumS,
        int* __restrict__ bbaseD, int* __restrict__ bbaseS, int NBK, int nE) {
    __shared__ int sh[256];
    int t = threadIdx.x;
    sh[t] = (t < NBK) ? (int)colsumD[t] : 0;
    __syncthreads();
    for (int off = 1; off < 256; off <<= 1) {
        int u = (t >= off) ? sh[t - off] : 0;
        __syncthreads();
        sh[t] += u;
        __syncthreads();
    }
    if (t < NBK) bbaseD[t] = (t == 0) ? 0 : sh[t - 1];
    if (t == 0) bbaseD[NBK] = nE;
    __syncthreads();
    sh[t] = (t < NBK) ? (int)colsumS[t] : 0;
    __syncthreads();
    for (int off = 1; off < 256; off <<= 1) {
        int u = (t >= off) ? sh[t - off] : 0;
        __syncthreads();
        sh[t] += u;
        __syncthreads();
    }
    if (t < NBK) bbaseS[t] = (t == 0) ? 0 : sh[t - 1];
    if (t == 0) bbaseS[NBK] = nE;
}

// phase 4: scatter with cursors initialized from the scanned matrix (no hist, no reserve)
__global__ __launch_bounds__(256) void k_scatter(
        const int* __restrict__ src, const int* __restrict__ dst,
        const unsigned int* __restrict__ cntD, const unsigned int* __restrict__ cntS,
        const int* __restrict__ bbaseD, const int* __restrict__ bbaseS,
        unsigned int* __restrict__ pairsD, unsigned short* __restrict__ srcL,
        int nE, int NBK, int nEB) {
    __shared__ int lcD[256], lcS[256];
    int t = threadIdx.x, b = blockIdx.x;
    for (int c = t; c < NBK; c += 256) {
        lcD[c] = bbaseD[c] + (int)cntD[c * nEB + b];
        lcS[c] = bbaseS[c] + (int)cntS[c * nEB + b];
    }
    __syncthreads();
    int base = b * 4096;
    #pragma unroll
    for (int i = 0; i < 16; ++i) {
        int e = base + i * 256 + t;
        if (e < nE) {
            int s = src[e], d = dst[e];
            int pD = atomicAdd(&lcD[d >> BSH], 1);
            pairsD[pD] = ((unsigned)s << BSH) | (unsigned)(d & (BW - 1));
            int pS = atomicAdd(&lcS[s >> BSH], 1);
            srcL[pS] = (unsigned short)(s & (BW - 1));
        }
    }
}

__global__ __launch_bounds__(512) void k_binD(
        const unsigned int* __restrict__ pairsD, const int* __restrict__ bbaseD,
        int* __restrict__ degI, int* __restrict__ offs,
        int* __restrict__ elist, int nN) {
    __shared__ int c0[BW], sh[BW], lcur[BW];
    int b = blockIdx.x, t = threadIdx.x;
    int p0 = bbaseD[b], p1 = bbaseD[b + 1];
    int n0 = b << BSH;
    c0[t] = 0;
    __syncthreads();
    for (int j = p0 + t; j < p1; j += 512)
        atomicAdd(&c0[pairsD[j] & (BW - 1u)], 1);
    __syncthreads();
    sh[t] = c0[t];
    __syncthreads();
    for (int off = 1; off < BW; off <<= 1) {
        int u = (t >= off) ? sh[t - off] : 0;
        __syncthreads();
        sh[t] += u;
        __syncthreads();
    }
    int excl = (t == 0) ? 0 : sh[t - 1];
    int node = n0 + t;
    if (node < nN) { degI[node] = c0[t]; offs[node] = p0 + excl; }
    lcur[t] = p0 + excl;
    __syncthreads();
    for (int j = p0 + t; j < p1; j += 512) {
        unsigned int pr = pairsD[j];
        int pos = atomicAdd(&lcur[pr & (BW - 1u)], 1);
        elist[pos] = (int)(pr >> BSH);
    }
}

__global__ __launch_bounds__(512) void k_binO(
        const unsigned short* __restrict__ srcL, const int* __restrict__ bbaseS,
        int* __restrict__ degO, int nN) {
    __shared__ int c0[BW];
    int b = blockIdx.x, t = threadIdx.x;
    int p0 = bbaseS[b], p1 = bbaseS[b + 1];
    c0[t] = 0;
    __syncthreads();
    for (int j = p0 + t; j < p1; j += 512)
        atomicAdd(&c0[srcL[j]], 1);
    __syncthreads();
    int node = (b << BSH) + t;
    if (node < nN) degO[node] = c0[t];
}

__global__ __launch_bounds__(256) void k_prep2(
        const float* __restrict__ heat, const int* __restrict__ degO,
        unsigned short* __restrict__ heatS, int nN) {
    int i = blockIdx.x * 256 + threadIdx.x;
    if (i >= nN * 32) return;
    int node = i >> 5;
    int c4 = (i & 31) << 2;
    float4 v = *reinterpret_cast<const float4*>(heat + ((size_t)node << 7) + c4);
    float sc = rsqrtf((float)max(degO[node], 1));
    unsigned int b0 = f2bf(v.x * sc), b1 = f2bf(v.y * sc);
    unsigned int b2 = f2bf(v.z * sc), b3 = f2bf(v.w * sc);
    uint2 p = make_uint2(b0 | (b1 << 16), b2 | (b3 << 16));
    *reinterpret_cast<uint2*>(heatS + ((size_t)node << 7) + c4) = p;
}

__global__ __launch_bounds__(256) void k_prepW(
        const float* __restrict__ W, unsigned short* __restrict__ WtB) {
    int idx = blockIdx.x * 256 + threadIdx.x;
    if (idx >= D * D) return;
    int k = idx >> 7, c = idx & 127;
    WtB[c * D + k] = (unsigned short)f2bf(W[idx]);
}

// one wave per node, 8-deep MLP; output bf16 raw sums
__global__ __launch_bounds__(256) void k_gather(
        const unsigned short* __restrict__ heatS, const int* __restrict__ elist,
        const int* __restrict__ offs, const int* __restrict__ degI,
        unsigned int* __restrict__ aggB, int nN) {
    int node = blockIdx.x * 4 + (threadIdx.x >> 6);
    if (node >= nN) return;
    int l = threadIdx.x & 63;
    size_t col = (size_t)(l << 1);
    int start = offs[node];
    int end = start + degI[node];
    float ax = 0.f, ay = 0.f;
    for (int jb = start; jb < end; jb += 64) {
        int cnt = min(64, end - jb);
        int sl = (l < cnt) ? elist[jb + l] : 0;
        int k = 0;
        for (; k + 8 <= cnt; k += 8) {
            unsigned int p0, p1, p2, p3, p4, p5, p6, p7;
            {
                int s0 = __shfl(sl, k + 0), s1 = __shfl(sl, k + 1);
                int s2 = __shfl(sl, k + 2), s3 = __shfl(sl, k + 3);
                int s4 = __shfl(sl, k + 4), s5 = __shfl(sl, k + 5);
                int s6 = __shfl(sl, k + 6), s7 = __shfl(sl, k + 7);
                p0 = *reinterpret_cast<const unsigned int*>(heatS + ((size_t)s0 << 7) + col);
                p1 = *reinterpret_cast<const unsigned int*>(heatS + ((size_t)s1 << 7) + col);
                p2 = *reinterpret_cast<const unsigned int*>(heatS + ((size_t)s2 << 7) + col);
                p3 = *reinterpret_cast<const unsigned int*>(heatS + ((size_t)s3 << 7) + col);
                p4 = *reinterpret_cast<const unsigned int*>(heatS + ((size_t)s4 << 7) + col);
                p5 = *reinterpret_cast<const unsigned int*>(heatS + ((size_t)s5 << 7) + col);
                p6 = *reinterpret_cast<const unsigned int*>(heatS + ((size_t)s6 << 7) + col);
                p7 = *reinterpret_cast<const unsigned int*>(heatS + ((size_t)s7 << 7) + col);
            }
            ax += __uint_as_float(p0 << 16) + __uint_as_float(p1 << 16)
                + __uint_as_float(p2 << 16) + __uint_as_float(p3 << 16)
                + __uint_as_float(p4 << 16) + __uint_as_float(p5 << 16)
                + __uint_as_float(p6 << 16) + __uint_as_float(p7 << 16);
            ay += __uint_as_float(p0 & 0xFFFF0000u) + __uint_as_float(p1 & 0xFFFF0000u)
                + __uint_as_float(p2 & 0xFFFF0000u) + __uint_as_float(p3 & 0xFFFF0000u)
                + __uint_as_float(p4 & 0xFFFF0000u) + __uint_as_float(p5 & 0xFFFF0000u)
                + __uint_as_float(p6 & 0xFFFF0000u) + __uint_as_float(p7 & 0xFFFF0000u);
        }
        for (; k < cnt; ++k) {
            int s = __shfl(sl, k);
            unsigned int p = *reinterpret_cast<const unsigned int*>(heatS + ((size_t)s << 7) + col);
            ax += __uint_as_float(p << 16);
            ay += __uint_as_float(p & 0xFFFF0000u);
        }
    }
    aggB[((size_t)node << 6) + l] = f2bf(ax) | (f2bf(ay) << 16);
}

// MFMA gemm: hB(bf16) = prelu( rsqrt(degI) * (aggB @ W) + b , a1 ), stats
#define BM 64
__global__ __launch_bounds__(256) void k_gemm(
        const unsigned short* __restrict__ aggB, const unsigned short* __restrict__ WtB,
        const float* __restrict__ b, const int* __restrict__ degI,
        const float* __restrict__ a1, unsigned short* __restrict__ hB,
        float* __restrict__ sums, float* __restrict__ sumsq, int nN) {
    __shared__ unsigned short sW[128 * 136];
    __shared__ float ss1[128], ss2[128];
    int t = threadIdx.x;
    {
        const unsigned int* Wu = (const unsigned int*)WtB;
        #pragma unroll
        for (int i = 0; i < 32; ++i) {
            int idx = t + i * 256;
            int c = idx >> 6;
            int kp = idx & 63;
            *(unsigned int*)&sW[c * 136 + kp * 2] = Wu[idx];
        }
    }
    if (t < 128) { ss1[t] = 0.f; ss2[t] = 0.f; }
    __syncthreads();

    int w = t >> 6;
    int l = t & 63;
    int lr = l & 15;
    int lq = l >> 4;
    int rowbase = blockIdx.x * BM + w * 16;

    f32x4 acc[8];
    #pragma unroll
    for (int ct = 0; ct < 8; ++ct) acc[ct] = (f32x4){0.f, 0.f, 0.f, 0.f};

    int arow = rowbase + lr;
    if (arow >= nN) arow = nN - 1;
    const unsigned short* arowp = aggB + ((size_t)arow << 7);

    #pragma unroll
    for (int ks = 0; ks < 4; ++ks) {
        bf16x8 afrag = *reinterpret_cast<const bf16x8*>(arowp + ks * 32 + lq * 8);
        #pragma unroll
        for (int ct = 0; ct < 8; ++ct) {
            bf16x8 bfrag = *reinterpret_cast<const bf16x8*>(
                &sW[(ct * 16 + lr) * 136 + ks * 32 + lq * 8]);
            acc[ct] = __builtin_amdgcn_mfma_f32_16x16x32_bf16(afrag, bfrag, acc[ct], 0, 0, 0);
        }
    }

    float alpha = a1[0];
    float s4v[4];
    int nv[4];
    #pragma unroll
    for (int j = 0; j < 4; ++j) {
        int n = rowbase + lq * 4 + j;
        nv[j] = n;
        s4v[j] = (n < nN) ? rsqrtf((float)max(degI[n], 1)) : 0.f;
    }
    #pragma unroll
    for (int ct = 0; ct < 8; ++ct) {
        int f = ct * 16 + lr;
        float bias = b[f];
        float p1 = 0.f, p2 = 0.f;
        #pragma unroll
        for (int j = 0; j < 4; ++j) {
            if (nv[j] < nN) {
                float v = acc[ct][j] * s4v[j] + bias;
                v = v > 0.f ? v : alpha * v;
                hB[((size_t)nv[j] << 7) + f] = (unsigned short)f2bf(v);
                p1 += v; p2 += v * v;
            }
        }
        atomicAdd(&ss1[f], p1);
        atomicAdd(&ss2[f], p2);
    }
    __syncthreads();
    if (t < 128) {
        int slot = blockIdx.x & 15;
        atomicAdd(&sums[slot * D + t], ss1[t]);
        atomicAdd(&sumsq[slot * D + t], ss2[t]);
    }
}

__global__ void k_finalize(
        const float* __restrict__ sums, const float* __restrict__ sumsq,
        const float* __restrict__ gamma, const float* __restrict__ beta,
        float* __restrict__ stats, int nN) {
    int f = threadIdx.x;
    float s1 = 0.f, s2 = 0.f;
    #pragma unroll
    for (int i = 0; i < 16; ++i) { s1 += sums[i * D + f]; s2 += sumsq[i * D + f]; }
    float inv_n = 1.0f / (float)nN;
    float mean = s1 * inv_n;
    float var = s2 * inv_n - mean * mean;
    float inv = rsqrtf(var + 1e-5f);
    float sc = gamma[f] * inv;
    stats[f] = sc;
    stats[D + f] = beta[f] - mean * sc;
}

// BN + PReLU: read bf16 h, write fp32 out
__global__ __launch_bounds__(256) void k_apply(
        const unsigned int* __restrict__ hB2, const float* __restrict__ stats,
        const float* __restrict__ a2, float* __restrict__ out, int total2) {
    int idx = blockIdx.x * 256 + threadIdx.x;
    if (idx >= total2) return;
    float alpha = a2[0];
    int j = idx & 31;
    uint2 p = reinterpret_cast<const uint2*>(hB2)[idx];
    float4 sc = *reinterpret_cast<const float4*>(stats + (j << 2));
    float4 sh = *reinterpret_cast<const float4*>(stats + D + (j << 2));
    float4 r;
    float v0 = __uint_as_float(p.x << 16);
    float v1 = __uint_as_float(p.x & 0xFFFF0000u);
    float v2 = __uint_as_float(p.y << 16);
    float v3 = __uint_as_float(p.y & 0xFFFF0000u);
    r.x = v0 * sc.x + sh.x; r.x = r.x > 0.f ? r.x : alpha * r.x;
    r.y = v1 * sc.y + sh.y; r.y = r.y > 0.f ? r.y : alpha * r.y;
    r.z = v2 * sc.z + sh.z; r.z = r.z > 0.f ? r.z : alpha * r.z;
    r.w = v3 * sc.w + sh.w; r.w = r.w > 0.f ? r.w : alpha * r.w;
    reinterpret_cast<float4*>(out)[idx] = r;
}

extern "C" void kernel_launch(void* const* d_in, const int* in_sizes, int n_in,
                              void* d_out, int out_size, void* d_ws, size_t ws_size,
                              hipStream_t stream) {
    const float* heat  = (const float*)d_in[0];
    const float* W     = (const float*)d_in[1];
    const float* b     = (const float*)d_in[2];
    const float* a1    = (const float*)d_in[3];
    const float* gamma = (const float*)d_in[4];
    const float* beta  = (const float*)d_in[5];
    const float* a2    = (const float*)d_in[6];
    const int*   src   = (const int*)d_in[7];
    const int*   dst   = (const int*)d_in[8];

    const int nN = in_sizes[0] / D;
    const int nE = in_sizes[7];
    const int NBK = (nN + BW - 1) >> BSH;      // 512-node buckets (196)
    const int nEB = (nE + 4095) / 4096;        // edge blocks (391), must be <= 512

    char* ws = (char*)d_ws;
    size_t o = 0;
    auto alloc = [&](size_t bytes) { size_t r = o; o = (o + bytes + 255) & ~(size_t)255; return r; };
    float* sums  = (float*)(ws + alloc(16 * D * 4));
    float* sumsq = (float*)(ws + alloc(16 * D * 4));
    size_t zero_end = o;                       // memset covers only sums+sumsq (16 KB)
    unsigned int* colsumD = (unsigned int*)(ws + alloc(256 * 4));
    unsigned int* colsumS = (unsigned int*)(ws + alloc(256 * 4));
    int*   bbaseD = (int*)(ws + alloc(257 * 4));
    int*   bbaseS = (int*)(ws + alloc(257 * 4));
    float* stats  = (float*)(ws + alloc(2 * D * 4));
    unsigned short* WtB = (unsigned short*)(ws + alloc((size_t)D * D * 2));
    unsigned int* cntD = (unsigned int*)(ws + alloc((size_t)NBK * nEB * 4));
    unsigned int* cntS = (unsigned int*)(ws + alloc((size_t)NBK * nEB * 4));
    int*   degO   = (int*)(ws + alloc((size_t)nN * 4));
    int*   degI   = (int*)(ws + alloc((size_t)nN * 4));
    int*   offs   = (int*)(ws + alloc((size_t)nN * 4));
    int*   elist  = (int*)(ws + alloc(((size_t)nE + 64) * 4));
    // aliased region: pairsD+srcL+heatS all dead before k_gemm writes hB
    size_t alias0 = o;
    unsigned int*   pairsD = (unsigned int*)(ws + alloc((size_t)nE * 4));
    unsigned short* srcL   = (unsigned short*)(ws + alloc((size_t)nE * 2));
    unsigned short* heatS  = (unsigned short*)(ws + alloc((size_t)nN * D * 2));
    unsigned int*   aggB   = (unsigned int*)(ws + alloc((size_t)nN * D * 2));
    unsigned short* hB     = (unsigned short*)(ws + alias0);
    float* outp = (float*)d_out;

    hipMemsetAsync(ws, 0, zero_end, stream);

    k_hist<<<nEB, 256, 0, stream>>>(src, dst, cntD, cntS, nE, NBK, nEB);
    k_colscan<<<2 * NBK, 512, 0, stream>>>(cntD, cntS, colsumD, colsumS, NBK, nEB);
    k_bscan3<<<1, 256, 0, stream>>>(colsumD, colsumS, bbaseD, bbaseS, NBK, nE);
    k_scatter<<<nEB, 256, 0, stream>>>(src, dst, cntD, cntS, bbaseD, bbaseS,
                                       pairsD, srcL, nE, NBK, nEB);
    k_binD<<<NBK, 512, 0, stream>>>(pairsD, bbaseD, degI, offs, elist, nN);
    k_binO<<<NBK, 512, 0, stream>>>(srcL, bbaseS, degO, nN);
    k_prepW<<<(D * D + 255) / 256, 256, 0, stream>>>(W, WtB);
    k_prep2<<<(nN * 32 + 255) / 256, 256, 0, stream>>>(heat, degO, heatS, nN);
    k_gather<<<(nN + 3) / 4, 256, 0, stream>>>(heatS, elist, offs, degI, aggB, nN);
    k_gemm<<<(nN + BM - 1) / BM, 256, 0, stream>>>(
        (const unsigned short*)aggB, WtB, b, degI, a1, hB, sums, sumsq, nN);
    k_finalize<<<1, 128, 0, stream>>>(sums, sumsq, gamma, beta, stats, nN);
    k_apply<<<(nN * 32 + 255) / 256, 256, 0, stream>>>(
        (const unsigned int*)hB, stats, a2, outp, nN * 32);
}

// Round 12
// 177.816 us; speedup vs baseline: 7.5534x; 1.1688x over previous
//
#include <hip/hip_runtime.h>

#define D 128
#define BSH 9
#define BW 512

typedef __attribute__((ext_vector_type(8))) short bf16x8;
typedef __attribute__((ext_vector_type(4))) float f32x4;

__device__ __forceinline__ unsigned int f2bf(float x) {
    unsigned int u = __float_as_uint(x);
    return (u + 0x7FFFu + ((u >> 16) & 1u)) >> 16;   // RNE
}

// phase 1: per-block LDS hist of dst/src buckets -> cnt matrices [bucket][block]
__global__ __launch_bounds__(256) void k_hist(
        const int* __restrict__ src, const int* __restrict__ dst,
        unsigned int* __restrict__ cntD, unsigned int* __restrict__ cntS,
        int nE, int NBK, int nEB) {
    __shared__ int lhD[256], lhS[256];
    int t = threadIdx.x, b = blockIdx.x;
    lhD[t] = 0; lhS[t] = 0;
    __syncthreads();
    int base = b * 4096;
    #pragma unroll
    for (int i = 0; i < 16; ++i) {
        int e = base + i * 256 + t;
        if (e < nE) {
            atomicAdd(&lhD[dst[e] >> BSH], 1);
            atomicAdd(&lhS[src[e] >> BSH], 1);
        }
    }
    __syncthreads();
    for (int c = t; c < NBK; c += 256) {
        cntD[c * nEB + b] = (unsigned)lhD[c];
        cntS[c * nEB + b] = (unsigned)lhS[c];
    }
}

// phase 2: per-bucket exclusive scan across blocks (in-place), emit column sums
// requires nEB <= 512
__global__ __launch_bounds__(512) void k_colscan(
        unsigned int* __restrict__ cntD, unsigned int* __restrict__ cntS,
        unsigned int* __restrict__ colsumD, unsigned int* __restrict__ colsumS,
        int NBK, int nEB) {
    __shared__ unsigned int sh[512];
    int t = threadIdx.x;
    int c = blockIdx.x;
    unsigned int* cnt;
    unsigned int* cs;
    if (c < NBK) { cnt = cntD; cs = colsumD; }
    else { cnt = cntS; cs = colsumS; c -= NBK; }
    unsigned v = (t < nEB) ? cnt[c * nEB + t] : 0u;
    sh[t] = v;
    __syncthreads();
    for (int off = 1; off < 512; off <<= 1) {
        unsigned u = (t >= off) ? sh[t - off] : 0u;
        __syncthreads();
        sh[t] += u;
        __syncthreads();
    }
    if (t < nEB) cnt[c * nEB + t] = sh[t] - v;      // exclusive prefix in-place
    if (t == 511) cs[c] = sh[511];
}

// phase 3: scatter; bucket bases computed locally from colsum (no global bscan)
__global__ __launch_bounds__(256) void k_scatter(
        const int* __restrict__ src, const int* __restrict__ dst,
        const unsigned int* __restrict__ cntD, const unsigned int* __restrict__ cntS,
        const unsigned int* __restrict__ colsumD, const unsigned int* __restrict__ colsumS,
        unsigned int* __restrict__ pairsD, unsigned short* __restrict__ srcL,
        int nE, int NBK, int nEB) {
    __shared__ int sh[256];
    __shared__ int lcD[256], lcS[256];
    int t = threadIdx.x, b = blockIdx.x;
    // local exclusive scan of colsumD -> dst bucket bases
    sh[t] = (t < NBK) ? (int)colsumD[t] : 0;
    __syncthreads();
    for (int off = 1; off < 256; off <<= 1) {
        int u = (t >= off) ? sh[t - off] : 0;
        __syncthreads();
        sh[t] += u;
        __syncthreads();
    }
    if (t < NBK) lcD[t] = ((t == 0) ? 0 : sh[t - 1]) + (int)cntD[t * nEB + b];
    __syncthreads();
    // local exclusive scan of colsumS -> src bucket bases
    sh[t] = (t < NBK) ? (int)colsumS[t] : 0;
    __syncthreads();
    for (int off = 1; off < 256; off <<= 1) {
        int u = (t >= off) ? sh[t - off] : 0;
        __syncthreads();
        sh[t] += u;
        __syncthreads();
    }
    if (t < NBK) lcS[t] = ((t == 0) ? 0 : sh[t - 1]) + (int)cntS[t * nEB + b];
    __syncthreads();
    int base = b * 4096;
    #pragma unroll
    for (int i = 0; i < 16; ++i) {
        int e = base + i * 256 + t;
        if (e < nE) {
            int s = src[e], d = dst[e];
            int pD = atomicAdd(&lcD[d >> BSH], 1);
            pairsD[pD] = ((unsigned)s << BSH) | (unsigned)(d & (BW - 1));
            int pS = atomicAdd(&lcS[s >> BSH], 1);
            srcL[pS] = (unsigned short)(s & (BW - 1));
        }
    }
}

// phase 4 merged: blocks [0,NBK) = dst-bin (degI/offs/elist), [NBK,2NBK) = src-bin (degO)
__global__ __launch_bounds__(512) void k_bin(
        const unsigned int* __restrict__ pairsD, const unsigned short* __restrict__ srcL,
        const unsigned int* __restrict__ colsumD, const unsigned int* __restrict__ colsumS,
        int* __restrict__ degI, int* __restrict__ offs, int* __restrict__ elist,
        int* __restrict__ degO, int nN, int NBK, int nE) {
    __shared__ int c0[BW], sh[BW], lcur[BW];
    int t = threadIdx.x;
    if (blockIdx.x < NBK) {
        int b = blockIdx.x;
        // local scan of colsumD for p0/p1
        sh[t] = (t < NBK) ? (int)colsumD[t] : 0;
        __syncthreads();
        for (int off = 1; off < BW; off <<= 1) {
            int u = (t >= off) ? sh[t - off] : 0;
            __syncthreads();
            sh[t] += u;
            __syncthreads();
        }
        int p0 = (b == 0) ? 0 : sh[b - 1];
        int p1 = sh[b];
        __syncthreads();
        int n0 = b << BSH;
        c0[t] = 0;
        __syncthreads();
        for (int j = p0 + t; j < p1; j += 512)
            atomicAdd(&c0[pairsD[j] & (BW - 1u)], 1);
        __syncthreads();
        sh[t] = c0[t];
        __syncthreads();
        for (int off = 1; off < BW; off <<= 1) {
            int u = (t >= off) ? sh[t - off] : 0;
            __syncthreads();
            sh[t] += u;
            __syncthreads();
        }
        int excl = (t == 0) ? 0 : sh[t - 1];
        int node = n0 + t;
        if (node < nN) { degI[node] = c0[t]; offs[node] = p0 + excl; }
        lcur[t] = p0 + excl;
        __syncthreads();
        for (int j = p0 + t; j < p1; j += 512) {
            unsigned int pr = pairsD[j];
            int pos = atomicAdd(&lcur[pr & (BW - 1u)], 1);
            elist[pos] = (int)(pr >> BSH);
        }
    } else {
        int b = blockIdx.x - NBK;
        sh[t] = (t < NBK) ? (int)colsumS[t] : 0;
        __syncthreads();
        for (int off = 1; off < BW; off <<= 1) {
            int u = (t >= off) ? sh[t - off] : 0;
            __syncthreads();
            sh[t] += u;
            __syncthreads();
        }
        int p0 = (b == 0) ? 0 : sh[b - 1];
        int p1 = sh[b];
        __syncthreads();
        c0[t] = 0;
        __syncthreads();
        for (int j = p0 + t; j < p1; j += 512)
            atomicAdd(&c0[srcL[j]], 1);
        __syncthreads();
        int node = (b << BSH) + t;
        if (node < nN) degO[node] = c0[t];
    }
}

// merged prep: blocks [0,nPB) = heatS scale+cast, [nPB, nPB+64) = W transpose+cast
__global__ __launch_bounds__(256) void k_prep(
        const float* __restrict__ heat, const int* __restrict__ degO,
        unsigned short* __restrict__ heatS,
        const float* __restrict__ W, unsigned short* __restrict__ WtB,
        int nN, int nPB) {
    int t = threadIdx.x;
    if ((int)blockIdx.x < nPB) {
        int i = blockIdx.x * 256 + t;
        if (i >= nN * 32) return;
        int node = i >> 5;
        int c4 = (i & 31) << 2;
        float4 v = *reinterpret_cast<const float4*>(heat + ((size_t)node << 7) + c4);
        float sc = rsqrtf((float)max(degO[node], 1));
        unsigned int b0 = f2bf(v.x * sc), b1 = f2bf(v.y * sc);
        unsigned int b2 = f2bf(v.z * sc), b3 = f2bf(v.w * sc);
        uint2 p = make_uint2(b0 | (b1 << 16), b2 | (b3 << 16));
        *reinterpret_cast<uint2*>(heatS + ((size_t)node << 7) + c4) = p;
    } else {
        int idx = (blockIdx.x - nPB) * 256 + t;
        if (idx >= D * D) return;
        int k = idx >> 7, c = idx & 127;
        WtB[c * D + k] = (unsigned short)f2bf(W[idx]);
    }
}

// one wave per node, 8-deep MLP; output bf16 raw sums
__global__ __launch_bounds__(256) void k_gather(
        const unsigned short* __restrict__ heatS, const int* __restrict__ elist,
        const int* __restrict__ offs, const int* __restrict__ degI,
        unsigned int* __restrict__ aggB, int nN) {
    int node = blockIdx.x * 4 + (threadIdx.x >> 6);
    if (node >= nN) return;
    int l = threadIdx.x & 63;
    size_t col = (size_t)(l << 1);
    int start = offs[node];
    int end = start + degI[node];
    float ax = 0.f, ay = 0.f;
    for (int jb = start; jb < end; jb += 64) {
        int cnt = min(64, end - jb);
        int sl = (l < cnt) ? elist[jb + l] : 0;
        int k = 0;
        for (; k + 8 <= cnt; k += 8) {
            unsigned int p0, p1, p2, p3, p4, p5, p6, p7;
            {
                int s0 = __shfl(sl, k + 0), s1 = __shfl(sl, k + 1);
                int s2 = __shfl(sl, k + 2), s3 = __shfl(sl, k + 3);
                int s4 = __shfl(sl, k + 4), s5 = __shfl(sl, k + 5);
                int s6 = __shfl(sl, k + 6), s7 = __shfl(sl, k + 7);
                p0 = *reinterpret_cast<const unsigned int*>(heatS + ((size_t)s0 << 7) + col);
                p1 = *reinterpret_cast<const unsigned int*>(heatS + ((size_t)s1 << 7) + col);
                p2 = *reinterpret_cast<const unsigned int*>(heatS + ((size_t)s2 << 7) + col);
                p3 = *reinterpret_cast<const unsigned int*>(heatS + ((size_t)s3 << 7) + col);
                p4 = *reinterpret_cast<const unsigned int*>(heatS + ((size_t)s4 << 7) + col);
                p5 = *reinterpret_cast<const unsigned int*>(heatS + ((size_t)s5 << 7) + col);
                p6 = *reinterpret_cast<const unsigned int*>(heatS + ((size_t)s6 << 7) + col);
                p7 = *reinterpret_cast<const unsigned int*>(heatS + ((size_t)s7 << 7) + col);
            }
            ax += __uint_as_float(p0 << 16) + __uint_as_float(p1 << 16)
                + __uint_as_float(p2 << 16) + __uint_as_float(p3 << 16)
                + __uint_as_float(p4 << 16) + __uint_as_float(p5 << 16)
                + __uint_as_float(p6 << 16) + __uint_as_float(p7 << 16);
            ay += __uint_as_float(p0 & 0xFFFF0000u) + __uint_as_float(p1 & 0xFFFF0000u)
                + __uint_as_float(p2 & 0xFFFF0000u) + __uint_as_float(p3 & 0xFFFF0000u)
                + __uint_as_float(p4 & 0xFFFF0000u) + __uint_as_float(p5 & 0xFFFF0000u)
                + __uint_as_float(p6 & 0xFFFF0000u) + __uint_as_float(p7 & 0xFFFF0000u);
        }
        for (; k < cnt; ++k) {
            int s = __shfl(sl, k);
            unsigned int p = *reinterpret_cast<const unsigned int*>(heatS + ((size_t)s << 7) + col);
            ax += __uint_as_float(p << 16);
            ay += __uint_as_float(p & 0xFFFF0000u);
        }
    }
    aggB[((size_t)node << 6) + l] = f2bf(ax) | (f2bf(ay) << 16);
}

// MFMA gemm: hB(bf16) = prelu( rsqrt(degI) * (aggB @ W) + b , a1 ), stats
#define BM 64
__global__ __launch_bounds__(256) void k_gemm(
        const unsigned short* __restrict__ aggB, const unsigned short* __restrict__ WtB,
        const float* __restrict__ b, const int* __restrict__ degI,
        const float* __restrict__ a1, unsigned short* __restrict__ hB,
        float* __restrict__ sums, float* __restrict__ sumsq, int nN) {
    __shared__ unsigned short sW[128 * 136];
    __shared__ float ss1[128], ss2[128];
    int t = threadIdx.x;
    {
        const unsigned int* Wu = (const unsigned int*)WtB;
        #pragma unroll
        for (int i = 0; i < 32; ++i) {
            int idx = t + i * 256;
            int c = idx >> 6;
            int kp = idx & 63;
            *(unsigned int*)&sW[c * 136 + kp * 2] = Wu[idx];
        }
    }
    if (t < 128) { ss1[t] = 0.f; ss2[t] = 0.f; }
    __syncthreads();

    int w = t >> 6;
    int l = t & 63;
    int lr = l & 15;
    int lq = l >> 4;
    int rowbase = blockIdx.x * BM + w * 16;

    f32x4 acc[8];
    #pragma unroll
    for (int ct = 0; ct < 8; ++ct) acc[ct] = (f32x4){0.f, 0.f, 0.f, 0.f};

    int arow = rowbase + lr;
    if (arow >= nN) arow = nN - 1;
    const unsigned short* arowp = aggB + ((size_t)arow << 7);

    #pragma unroll
    for (int ks = 0; ks < 4; ++ks) {
        bf16x8 afrag = *reinterpret_cast<const bf16x8*>(arowp + ks * 32 + lq * 8);
        #pragma unroll
        for (int ct = 0; ct < 8; ++ct) {
            bf16x8 bfrag = *reinterpret_cast<const bf16x8*>(
                &sW[(ct * 16 + lr) * 136 + ks * 32 + lq * 8]);
            acc[ct] = __builtin_amdgcn_mfma_f32_16x16x32_bf16(afrag, bfrag, acc[ct], 0, 0, 0);
        }
    }

    float alpha = a1[0];
    float s4v[4];
    int nv[4];
    #pragma unroll
    for (int j = 0; j < 4; ++j) {
        int n = rowbase + lq * 4 + j;
        nv[j] = n;
        s4v[j] = (n < nN) ? rsqrtf((float)max(degI[n], 1)) : 0.f;
    }
    #pragma unroll
    for (int ct = 0; ct < 8; ++ct) {
        int f = ct * 16 + lr;
        float bias = b[f];
        float p1 = 0.f, p2 = 0.f;
        #pragma unroll
        for (int j = 0; j < 4; ++j) {
            if (nv[j] < nN) {
                float v = acc[ct][j] * s4v[j] + bias;
                v = v > 0.f ? v : alpha * v;
                hB[((size_t)nv[j] << 7) + f] = (unsigned short)f2bf(v);
                p1 += v; p2 += v * v;
            }
        }
        // reduce over the 4 lq-lanes sharing feature f, then single atomic
        p1 += __shfl_xor(p1, 16); p1 += __shfl_xor(p1, 32);
        p2 += __shfl_xor(p2, 16); p2 += __shfl_xor(p2, 32);
        if (lq == 0) {
            atomicAdd(&ss1[f], p1);
            atomicAdd(&ss2[f], p2);
        }
    }
    __syncthreads();
    if (t < 128) {
        int slot = blockIdx.x & 15;
        atomicAdd(&sums[slot * D + t], ss1[t]);
        atomicAdd(&sumsq[slot * D + t], ss2[t]);
    }
}

__global__ void k_finalize(
        const float* __restrict__ sums, const float* __restrict__ sumsq,
        const float* __restrict__ gamma, const float* __restrict__ beta,
        float* __restrict__ stats, int nN) {
    int f = threadIdx.x;
    float s1 = 0.f, s2 = 0.f;
    #pragma unroll
    for (int i = 0; i < 16; ++i) { s1 += sums[i * D + f]; s2 += sumsq[i * D + f]; }
    float inv_n = 1.0f / (float)nN;
    float mean = s1 * inv_n;
    float var = s2 * inv_n - mean * mean;
    float inv = rsqrtf(var + 1e-5f);
    float sc = gamma[f] * inv;
    stats[f] = sc;
    stats[D + f] = beta[f] - mean * sc;
}

// BN + PReLU: read bf16 h, write fp32 out
__global__ __launch_bounds__(256) void k_apply(
        const unsigned int* __restrict__ hB2, const float* __restrict__ stats,
        const float* __restrict__ a2, float* __restrict__ out, int total2) {
    int idx = blockIdx.x * 256 + threadIdx.x;
    if (idx >= total2) return;
    float alpha = a2[0];
    int j = idx & 31;
    uint2 p = reinterpret_cast<const uint2*>(hB2)[idx];
    float4 sc = *reinterpret_cast<const float4*>(stats + (j << 2));
    float4 sh = *reinterpret_cast<const float4*>(stats + D + (j << 2));
    float4 r;
    float v0 = __uint_as_float(p.x << 16);
    float v1 = __uint_as_float(p.x & 0xFFFF0000u);
    float v2 = __uint_as_float(p.y << 16);
    float v3 = __uint_as_float(p.y & 0xFFFF0000u);
    r.x = v0 * sc.x + sh.x; r.x = r.x > 0.f ? r.x : alpha * r.x;
    r.y = v1 * sc.y + sh.y; r.y = r.y > 0.f ? r.y : alpha * r.y;
    r.z = v2 * sc.z + sh.z; r.z = r.z > 0.f ? r.z : alpha * r.z;
    r.w = v3 * sc.w + sh.w; r.w = r.w > 0.f ? r.w : alpha * r.w;
    reinterpret_cast<float4*>(out)[idx] = r;
}

extern "C" void kernel_launch(void* const* d_in, const int* in_sizes, int n_in,
                              void* d_out, int out_size, void* d_ws, size_t ws_size,
                              hipStream_t stream) {
    const float* heat  = (const float*)d_in[0];
    const float* W     = (const float*)d_in[1];
    const float* b     = (const float*)d_in[2];
    const float* a1    = (const float*)d_in[3];
    const float* gamma = (const float*)d_in[4];
    const float* beta  = (const float*)d_in[5];
    const float* a2    = (const float*)d_in[6];
    const int*   src   = (const int*)d_in[7];
    const int*   dst   = (const int*)d_in[8];

    const int nN = in_sizes[0] / D;
    const int nE = in_sizes[7];
    const int NBK = (nN + BW - 1) >> BSH;      // 512-node buckets (196)
    const int nEB = (nE + 4095) / 4096;        // edge blocks (391), must be <= 512
    const int nPB = (nN * 32 + 255) / 256;     // prep2 blocks

    char* ws = (char*)d_ws;
    size_t o = 0;
    auto alloc = [&](size_t bytes) { size_t r = o; o = (o + bytes + 255) & ~(size_t)255; return r; };
    float* sums  = (float*)(ws + alloc(16 * D * 4));
    float* sumsq = (float*)(ws + alloc(16 * D * 4));
    size_t zero_end = o;                       // memset covers only sums+sumsq (16 KB)
    unsigned int* colsumD = (unsigned int*)(ws + alloc(256 * 4));
    unsigned int* colsumS = (unsigned int*)(ws + alloc(256 * 4));
    float* stats  = (float*)(ws + alloc(2 * D * 4));
    unsigned short* WtB = (unsigned short*)(ws + alloc((size_t)D * D * 2));
    unsigned int* cntD = (unsigned int*)(ws + alloc((size_t)NBK * nEB * 4));
    unsigned int* cntS = (unsigned int*)(ws + alloc((size_t)NBK * nEB * 4));
    int*   degO   = (int*)(ws + alloc((size_t)nN * 4));
    int*   degI   = (int*)(ws + alloc((size_t)nN * 4));
    int*   offs   = (int*)(ws + alloc((size_t)nN * 4));
    int*   elist  = (int*)(ws + alloc(((size_t)nE + 64) * 4));
    // aliased region: pairsD+srcL+heatS all dead before k_gemm writes hB
    size_t alias0 = o;
    unsigned int*   pairsD = (unsigned int*)(ws + alloc((size_t)nE * 4));
    unsigned short* srcL   = (unsigned short*)(ws + alloc((size_t)nE * 2));
    unsigned short* heatS  = (unsigned short*)(ws + alloc((size_t)nN * D * 2));
    unsigned int*   aggB   = (unsigned int*)(ws + alloc((size_t)nN * D * 2));
    unsigned short* hB     = (unsigned short*)(ws + alias0);
    float* outp = (float*)d_out;

    hipMemsetAsync(ws, 0, zero_end, stream);

    k_hist<<<nEB, 256, 0, stream>>>(src, dst, cntD, cntS, nE, NBK, nEB);
    k_colscan<<<2 * NBK, 512, 0, stream>>>(cntD, cntS, colsumD, colsumS, NBK, nEB);
    k_scatter<<<nEB, 256, 0, stream>>>(src, dst, cntD, cntS, colsumD, colsumS,
                                       pairsD, srcL, nE, NBK, nEB);
    k_bin<<<2 * NBK, 512, 0, stream>>>(pairsD, srcL, colsumD, colsumS,
                                       degI, offs, elist, degO, nN, NBK, nE);
    k_prep<<<nPB + 64, 256, 0, stream>>>(heat, degO, heatS, W, WtB, nN, nPB);
    k_gather<<<(nN + 3) / 4, 256, 0, stream>>>(heatS, elist, offs, degI, aggB, nN);
    k_gemm<<<(nN + BM - 1) / BM, 256, 0, stream>>>(
        (const unsigned short*)aggB, WtB, b, degI, a1, hB, sums, sumsq, nN);
    k_finalize<<<1, 128, 0, stream>>>(sums, sumsq, gamma, beta, stats, nN);
    k_apply<<<(nN * 32 + 255) / 256, 256, 0, stream>>>(
        (const unsigned int*)hB, stats, a2, outp, nN * 32);
}